// Round 5
// baseline (2497.420 us; speedup 1.0000x reference)
//
#include <hip/hip_runtime.h>
#include <stdint.h>

// ============================================================================
// LSTM (B=2048,T=256,D=32,H=256) + FC(256) on gfx950.
// R5: NO inter-block communication. 256 blocks x 1024 thr (16 waves),
// tileB=8 (M=8 zero-padded into 16x16 MFMA). Each wave owns one 16-hidden-
// unit group x 4 gates and keeps its 36 weight frags (9 ktiles x 4 gates =
// 144 regs) resident for all 256 steps; h/c never leave the CU. Per step:
// 36 MFMA/wave + z scatter to LDS + balanced gate phase (2 valid cells per
// thread across all 1024 threads -- halves transcendental serialization vs
// computing the C-layout's junk rows) + 2 intra-CU barriers. R4's 3.6us/step
// L3 exchange chain (store-ack, flag RTT, poll, load; 266MB HBM writes) is
// gone entirely.
// MFMA layouts (learn_hip verified): A[m=lane&15][k=(lane>>4)*8+j],
// B^T same, C/D: col=lane&15, row=(lane>>4)*4+reg.
// ============================================================================

typedef __attribute__((ext_vector_type(8))) short short8;
typedef __attribute__((ext_vector_type(4))) float f32x4;

#define LDSTRIDE 296  // shorts per A row (288 + 8 pad)
#define ZROW 1028     // floats per Z row (256*4 + 4 pad: breaks quad aliasing)

__device__ __forceinline__ short f2bf(float f) {
  uint32_t u = __builtin_bit_cast(uint32_t, f);
  u = (u + 0x7FFFu + ((u >> 16) & 1u)) >> 16;  // RNE
  return (short)(uint16_t)u;
}

#define LOG2E 1.4426950408889634f
__device__ __forceinline__ float sigmoidf_(float x) {
  return __builtin_amdgcn_rcpf(1.0f + __builtin_amdgcn_exp2f(-LOG2E * x));
}
__device__ __forceinline__ float tanhf_(float x) {
  float t = __builtin_amdgcn_exp2f((2.0f * LOG2E) * x);
  return 1.0f - 2.0f * __builtin_amdgcn_rcpf(t + 1.0f);
}

// ---------------------------------------------------------------------------
// Pack W_hh[1024x256] (k 0..255) + W_ih[1024x32] (k 256..287) into bf16 frags.
// frag = (kt*16 + hu)*4 + g ; element (lane,j):
//   n = g*256 + hu*16 + (lane&15), k = kt*32 + (lane>>4)*8 + j
// ---------------------------------------------------------------------------
__global__ void pack_w(const float* __restrict__ Whh, const float* __restrict__ Wih,
                       short* __restrict__ wpack) {
  int tid = blockIdx.x * 256 + threadIdx.x;  // 576 frags * 64 lanes = 36864
  if (tid >= 576 * 64) return;
  int lane = tid & 63;
  int frag = tid >> 6;
  int g = frag & 3, hu = (frag >> 2) & 15, kt = frag >> 6;
  int n = g * 256 + hu * 16 + (lane & 15);
  int k0 = kt * 32 + (lane >> 4) * 8;
  short8 v;
#pragma unroll
  for (int j = 0; j < 8; ++j) {
    int k = k0 + j;
    float f = (k < 256) ? Whh[n * 256 + k] : Wih[n * 32 + (k - 256)];
    v[j] = f2bf(f);
  }
  *(short8*)(wpack + (size_t)frag * 512 + lane * 8) = v;
}

// W_fc[256x256] -> frags (kt 0..7, ct 0..15): n = ct*16+(lane&15).
__global__ void pack_wfc(const float* __restrict__ Wfc, short* __restrict__ wfc) {
  int tid = blockIdx.x * 256 + threadIdx.x;  // 128 frags * 64 lanes
  if (tid >= 128 * 64) return;
  int lane = tid & 63;
  int frag = tid >> 6;
  int ct = frag & 15, kt = frag >> 4;
  int n = ct * 16 + (lane & 15);
  int k0 = kt * 32 + (lane >> 4) * 8;
  short8 v;
#pragma unroll
  for (int j = 0; j < 8; ++j) v[j] = f2bf(Wfc[n * 256 + k0 + j]);
  *(short8*)(wfc + (size_t)frag * 512 + lane * 8) = v;
}

// ---------------------------------------------------------------------------
// Main kernel: grid 256 (bt = blockIdx.x, rows bt*8..+8), block 1024.
// Wave w (0..15): hidden units w*16..+16, all 4 gates, weights in regs.
// ---------------------------------------------------------------------------
__global__ __launch_bounds__(1024, 4) void lstm_main(
    const float* __restrict__ obs, const short8* __restrict__ wpack,
    const short8* __restrict__ wfc, const float* __restrict__ b_ih,
    const float* __restrict__ b_hh, const float* __restrict__ b_fc,
    float* __restrict__ out) {
  __shared__ __align__(16) short A[16 * LDSTRIDE];  // rows 8..15 stay ZERO
  __shared__ __align__(16) float Z[8 * ZROW];       // z scatter: [row][hid*4+g]
  const int tid = threadIdx.x;
  const int w = tid >> 6, lane = tid & 63;
  const int l15 = lane & 15, quad = lane >> 4;
  const int row0 = blockIdx.x * 8;
  // gate-phase cell assignment: 2048 valid cells, 2 per thread (same row,
  // adjacent hidden units -> one aligned 8-float Z read, one b32 h write)
  const int crow = tid >> 7;           // 0..7
  const int hid0 = (tid & 127) * 2;    // even

  // zero A once (h_0 = 0; rows 8..15 remain zero forever)
  for (int i = tid; i < 16 * LDSTRIDE; i += 1024) A[i] = 0;

  // persistent weight registers: 36 frags = 144 regs (constant indices only)
  short8 wfr[9][4];
#pragma unroll
  for (int kt = 0; kt < 9; ++kt)
#pragma unroll
    for (int g = 0; g < 4; ++g)
      wfr[kt][g] = wpack[(size_t)((kt * 16 + w) * 4 + g) * 64 + lane];

  // per-thread gate biases for its two cells
  float bias2[2][4];
#pragma unroll
  for (int ci = 0; ci < 2; ++ci)
#pragma unroll
    for (int g = 0; g < 4; ++g) {
      int idx = g * 256 + hid0 + ci;
      bias2[ci][g] = b_ih[idx] + b_hh[idx];
    }

  float c2[2] = {0.f, 0.f};

  __syncthreads();
  // stage x_0 (8 rows x 32 d)
  if (tid < 256) {
    int xr = tid >> 5, xd = tid & 31;
    A[xr * LDSTRIDE + 256 + xd] = f2bf(obs[((size_t)(row0 + xr) * 256 + 0) * 32 + xd]);
  }
  __syncthreads();

  for (int t = 0; t < 256; ++t) {
    // prefetch x_{t+1} (used after barrier1; latency hidden by GEMM)
    float xv = 0.f;
    if (tid < 256) {
      const int tn = (t < 255) ? (t + 1) : 255;
      xv = obs[((size_t)(row0 + (tid >> 5)) * 256 + tn) * 32 + (tid & 31)];
    }

    f32x4 acc[4];
#pragma unroll
    for (int g = 0; g < 4; ++g) acc[g] = (f32x4){0.f, 0.f, 0.f, 0.f};

    // GEMM: z[8(pad16) x 64 cols of this wave], K = 288 = 9*32
#pragma unroll
    for (int kt = 0; kt < 9; ++kt) {
      const short8 a = *(const short8*)&A[l15 * LDSTRIDE + kt * 32 + quad * 8];
#pragma unroll
      for (int g = 0; g < 4; ++g)
        acc[g] = __builtin_amdgcn_mfma_f32_16x16x32_bf16(a, wfr[kt][g], acc[g], 0, 0, 0);
    }

    // scatter valid z (rows 0..7 = quads 0,1) to Z: [row][hid*4 + g]
    if (lane < 32) {
      const int hcol = (w * 16 + l15) * 4;
#pragma unroll
      for (int r = 0; r < 4; ++r)
#pragma unroll
        for (int g = 0; g < 4; ++g)
          Z[(quad * 4 + r) * ZROW + hcol + g] = acc[g][r];
    }
    __syncthreads();  // Z complete; all A reads done

    // balanced gate phase: 2 cells/thread
    const f32x4 z0 = *(const f32x4*)&Z[crow * ZROW + hid0 * 4];
    const f32x4 z1 = *(const f32x4*)&Z[crow * ZROW + hid0 * 4 + 4];
    float h0, h1;
    {
      float iv = sigmoidf_(z0[0] + bias2[0][0]);
      float fv = sigmoidf_(z0[1] + bias2[0][1]);
      float gv = tanhf_(z0[2] + bias2[0][2]);
      float ov = sigmoidf_(z0[3] + bias2[0][3]);
      float cc = fv * c2[0] + iv * gv;
      c2[0] = cc;
      h0 = ov * tanhf_(cc);
    }
    {
      float iv = sigmoidf_(z1[0] + bias2[1][0]);
      float fv = sigmoidf_(z1[1] + bias2[1][1]);
      float gv = tanhf_(z1[2] + bias2[1][2]);
      float ov = sigmoidf_(z1[3] + bias2[1][3]);
      float cc = fv * c2[1] + iv * gv;
      c2[1] = cc;
      h1 = ov * tanhf_(cc);
    }
    // h pair (adjacent hidden units, same row) -> one b32 LDS write
    uint32_t hp = (uint32_t)(uint16_t)f2bf(h0) | ((uint32_t)(uint16_t)f2bf(h1) << 16);
    *(uint32_t*)&A[crow * LDSTRIDE + hid0] = hp;
    // x_{t+1}
    if (tid < 256)
      A[(tid >> 5) * LDSTRIDE + 256 + (tid & 31)] = f2bf(xv);
    __syncthreads();  // h_{t+1} + x_{t+1} visible for next GEMM
  }

  // FC epilogue: out[8 x 256] = h_last @ W_fc^T + b_fc; wave w -> cols w*16..+16
  f32x4 ao = (f32x4){0.f, 0.f, 0.f, 0.f};
#pragma unroll
  for (int kt = 0; kt < 8; ++kt) {
    const short8 a = *(const short8*)&A[l15 * LDSTRIDE + kt * 32 + quad * 8];
    const short8 b = wfc[(size_t)(kt * 16 + w) * 64 + lane];
    ao = __builtin_amdgcn_mfma_f32_16x16x32_bf16(a, b, ao, 0, 0, 0);
  }
  if (quad < 2) {  // valid out rows 0..7
    const int col = w * 16 + l15;
    const float bv = b_fc[col];
#pragma unroll
    for (int reg = 0; reg < 4; ++reg) {
      const int row = row0 + quad * 4 + reg;
      out[(size_t)row * 256 + col] = ao[reg] + bv;
    }
  }
}

extern "C" void kernel_launch(void* const* d_in, const int* in_sizes, int n_in,
                              void* d_out, int out_size, void* d_ws, size_t ws_size,
                              hipStream_t stream) {
  const float* obs  = (const float*)d_in[0];   // [2048,256,32]
  const float* W_ih = (const float*)d_in[1];   // [1024,32]
  const float* W_hh = (const float*)d_in[2];   // [1024,256]
  const float* b_ih = (const float*)d_in[3];   // [1024]
  const float* b_hh = (const float*)d_in[4];   // [1024]
  const float* W_fc = (const float*)d_in[5];   // [256,256]
  const float* b_fc = (const float*)d_in[6];   // [256]
  float* out = (float*)d_out;                  // [2048,256]

  short* wpack = (short*)d_ws;                 // 576*512 shorts = 576 KB
  short* wfcp  = wpack + 576 * 512;            // 128*512 shorts = 128 KB

  hipLaunchKernelGGL(pack_w, dim3(144), dim3(256), 0, stream, W_hh, W_ih, wpack);
  hipLaunchKernelGGL(pack_wfc, dim3(32), dim3(256), 0, stream, W_fc, wfcp);
  hipLaunchKernelGGL(lstm_main, dim3(256), dim3(1024), 0, stream, obs,
                     (const short8*)wpack, (const short8*)wfcp,
                     b_ih, b_hh, b_fc, out);
}